// Round 6
// baseline (319.722 us; speedup 1.0000x reference)
//
#include <hip/hip_runtime.h>
#include <hip/hip_bf16.h>
#include <stdint.h>

#define B_   4
#define S_   1024
#define H_   1024      // hidden
#define NH_  16        // ENT
#define D_   64        // INNER
#define N1_  2048      // ENT*2*INNER
#define M1_  4096      // B*S
#define NEG_ 1000000000000.0f

typedef __attribute__((ext_vector_type(8))) short bf16x8;
typedef __attribute__((ext_vector_type(4))) float f32x4;

__device__ inline void gload_lds16(const void* g, void* l) {
  __builtin_amdgcn_global_load_lds(
      (const __attribute__((address_space(1))) unsigned int*)g,
      (__attribute__((address_space(3))) unsigned int*)l, 16, 0, 0);
}

__device__ inline unsigned short f2bf(float f) {
  union { float f; uint32_t u; } a; a.f = f;
  uint32_t r = a.u + 0x7fff + ((a.u >> 16) & 1);   // RNE
  return (unsigned short)(r >> 16);
}

// ---------------- fused prep: cast + transW + sincos in one launch ----------------

__global__ __launch_bounds__(256) void k_prep(
    const float4* __restrict__ lhs4, unsigned short* __restrict__ lhsb,
    const float* __restrict__ W, unsigned short* __restrict__ WT,
    float* __restrict__ tab) {
  __shared__ float tsm[32][33];
  int b = blockIdx.x, t = threadIdx.x;
  if (b < 4096) {
    int i = b * 256 + t;          // < 1048576 always
    float4 v = lhs4[i];
    uint64_t pk = (uint64_t)f2bf(v.x) | ((uint64_t)f2bf(v.y) << 16) |
                  ((uint64_t)f2bf(v.z) << 32) | ((uint64_t)f2bf(v.w) << 48);
    ((uint64_t*)lhsb)[i] = pk;
  } else if (b < 6144) {
    int bb = b - 4096;            // 0..2047
    int nb = (bb & 63) * 32, kb = (bb >> 6) * 32;
    int tx = t & 31, ty = t >> 5; // (32,8)
    for (int r = 0; r < 4; r++)
      tsm[ty + r * 8][tx] = W[(size_t)(kb + ty + r * 8) * N1_ + nb + tx];
    __syncthreads();
    for (int r = 0; r < 4; r++)
      WT[(size_t)(nb + ty + r * 8) * H_ + kb + tx] = f2bf(tsm[tx][ty + r * 8]);
  } else {
    int i = (b - 6144) * 256 + t; // < 32768
    int pos = i >> 5, fi = i & 31;
    float freq = exp2f(-(float)fi * (13.2877123795494f / 32.0f)); // 10000^(-2fi/64)
    float ang = (float)pos * freq;
    tab[2 * i]     = sinf(ang);
    tab[2 * i + 1] = cosf(ang);
  }
}

// ---------------- stage 1: P = lhs @ W + b, fused RoPE, scatter to q/k ----------------
// Round-5 post-mortem: __syncthreads() drains vmcnt(0) -> dbuf prefetch never
// overlapped (m99/m100 reproduced). Round-6: counted-vmcnt 2-deep pipeline with
// RAW s_barrier (T4/m218 recipe). Invariant: 8 loads outstanding at every loop
// head; oldest 4 = current buffer. No vmcnt(0) in the main loop.

__global__ __launch_bounds__(256) void k_gemm1(
    const unsigned short* __restrict__ A,   // M1_ x H_ bf16
    const unsigned short* __restrict__ BT,  // N1_ x H_ bf16
    const float* __restrict__ bias,         // N1_
    const float* __restrict__ sc,           // sin/cos table
    unsigned short* __restrict__ qws,       // [B*NH][S][D] bf16
    unsigned short* __restrict__ kws) {
  __shared__ unsigned short a_lds[2][128 * 32];
  __shared__ unsigned short b_lds[2][128 * 32];
  int t = threadIdx.x;
  int lane = t & 63, wv = t >> 6;
  int wm = wv >> 1, wn = wv & 1;
  int col = lane & 15, quad = lane >> 4;
  int swz8 = (quad ^ ((col >> 1) & 3)) * 8;   // reader slot offset (shorts)

  int l = blockIdx.x;
  int xcd = l & 7, k = l >> 3;
  int mBase = (((k & 3) << 3) + xcd) * 128;   // 32 m-tiles
  int nBase = (k >> 2) * 128;                 // 16 n-tiles

  // per-thread staging coords (constant across K-steps)
  int idx0 = t;            // c=0
  int idx1 = 256 + t;      // c=1
  int r0 = idx0 >> 2, ch0 = (idx0 & 3) ^ ((r0 >> 1) & 3);
  int r1 = idx1 >> 2, ch1 = (idx1 & 3) ^ ((r1 >> 1) & 3);
  const unsigned short* Arow0 = A + (size_t)(mBase + r0) * H_ + ch0 * 8;
  const unsigned short* Arow1 = A + (size_t)(mBase + r1) * H_ + ch1 * 8;
  const unsigned short* Brow0 = BT + (size_t)(nBase + r0) * H_ + ch0 * 8;
  const unsigned short* Brow1 = BT + (size_t)(nBase + r1) * H_ + ch1 * 8;

  f32x4 acc[4][4] = {};   // [j: n-tile][i: m-tile]

  // prologue: stage K-step 0 -> buf0, K-step 1 -> buf1 (8 loads in flight)
  gload_lds16(Arow0,      &a_lds[0][idx0 * 8]);
  gload_lds16(Brow0,      &b_lds[0][idx0 * 8]);
  gload_lds16(Arow1,      &a_lds[0][idx1 * 8]);
  gload_lds16(Brow1,      &b_lds[0][idx1 * 8]);
  gload_lds16(Arow0 + 32, &a_lds[1][idx0 * 8]);
  gload_lds16(Brow0 + 32, &b_lds[1][idx0 * 8]);
  gload_lds16(Arow1 + 32, &a_lds[1][idx1 * 8]);
  gload_lds16(Brow1 + 32, &b_lds[1][idx1 * 8]);

  int p = 0;
#pragma unroll 1
  for (int kk = 0; kk < H_; kk += 32) {
    // oldest 4 outstanding loads = buf[p] (this step's data); newer 4 stay in flight
    asm volatile("s_waitcnt vmcnt(4)" ::: "memory");
    __builtin_amdgcn_sched_barrier(0);
    __builtin_amdgcn_s_barrier();          // buf[p] visible block-wide
    __builtin_amdgcn_sched_barrier(0);

    bf16x8 af[4], bf[4];
#pragma unroll
    for (int i = 0; i < 4; i++)
      af[i] = *(const bf16x8*)&a_lds[p][(wm * 64 + i * 16 + col) * 32 + swz8];
#pragma unroll
    for (int j = 0; j < 4; j++)
      bf[j] = *(const bf16x8*)&b_lds[p][(wn * 64 + j * 16 + col) * 32 + swz8];

    asm volatile("s_waitcnt lgkmcnt(0)" ::: "memory");
    __builtin_amdgcn_sched_barrier(0);     // rule #18: pin MFMA below the wait
    __builtin_amdgcn_s_barrier();          // all waves done reading buf[p]
    __builtin_amdgcn_sched_barrier(0);

    // prefetch K-step k+2 into buf[p] (clamped in last 2 iters: data unused,
    // keeps the outstanding-load count invariant and stays in bounds)
    {
      int kpre = kk + 64; if (kpre > H_ - 32) kpre = H_ - 32;
      gload_lds16(Arow0 + kpre, &a_lds[p][idx0 * 8]);
      gload_lds16(Brow0 + kpre, &b_lds[p][idx0 * 8]);
      gload_lds16(Arow1 + kpre, &a_lds[p][idx1 * 8]);
      gload_lds16(Brow1 + kpre, &b_lds[p][idx1 * 8]);
    }
    __builtin_amdgcn_sched_barrier(0);     // loads issue before the MFMA burst

#pragma unroll
    for (int j = 0; j < 4; j++)
#pragma unroll
      for (int i = 0; i < 4; i++)
        acc[j][i] = __builtin_amdgcn_mfma_f32_16x16x32_bf16(bf[j], af[i], acc[j][i], 0, 0, 0);
    p ^= 1;
  }

  // epilogue: bias + interleaved RoPE (pairs in-lane) + ushort4 scatter
#pragma unroll
  for (int i = 0; i < 4; i++) {
    int m = mBase + wm * 64 + i * 16 + col;      // 0..4095
    int pos = m & (S_ - 1);
    int bb = m >> 10;
#pragma unroll
    for (int j = 0; j < 4; j++) {
      int n = nBase + wn * 64 + j * 16 + quad * 4;  // 4-aligned
      int d = n & 63;
      int head = n >> 7;
      int isK = (n >> 6) & 1;
      float4 bj  = *(const float4*)&bias[n];
      float4 scv = *(const float4*)&sc[(pos * 32 + (d >> 1)) * 2]; // s0,c0,s1,c1
      float v0 = acc[j][i][0] + bj.x;
      float v1 = acc[j][i][1] + bj.y;
      float v2 = acc[j][i][2] + bj.z;
      float v3 = acc[j][i][3] + bj.w;
      float o0 = v0 * scv.y - v1 * scv.x;
      float o1 = v1 * scv.y + v0 * scv.x;
      float o2 = v2 * scv.w - v3 * scv.z;
      float o3 = v3 * scv.w + v2 * scv.z;
      unsigned short* dst = isK ? kws : qws;
      ushort4 pk;
      pk.x = f2bf(o0); pk.y = f2bf(o1); pk.z = f2bf(o2); pk.w = f2bf(o3);
      *(ushort4*)&dst[((size_t)(bb * NH_ + head) * S_ + pos) * D_ + d] = pk;
    }
  }
}

// ---------------- stage 2: logits[b,h] = Q K^T with masks ----------------
// (byte-identical to round 3 for attribution)

#define STG_ 132   // stage row stride in floats

__global__ __launch_bounds__(256) void k_gemm2(
    const unsigned short* __restrict__ qws,
    const unsigned short* __restrict__ kws,
    const float* __restrict__ tl,           // (B, S)
    float* __restrict__ out) {
  __shared__ __align__(16) char smem[64 * STG_ * 4];   // 33792 B >= 32768 B
  unsigned short* q_lds = (unsigned short*)smem;
  unsigned short* k_lds = q_lds + 128 * 64;
  float* stage = (float*)smem;

  int t = threadIdx.x;
  int lane = t & 63, wv = t >> 6, wm = wv >> 1, wn = wv & 1;
  int col = lane & 15, quad = lane >> 4;

  int l = blockIdx.x;                 // 0..4095
  int xcd = l & 7, k = l >> 3;        // k: 0..511
  int z = (xcd << 3) + (k >> 6);      // 0..63 (b*16+h)
  int tile = k & 63;
  int mt = tile >> 3, nt = tile & 7;
  int mT = mt * 128, nT = nt * 128;
  int bb = z >> 4;

  if (nt < mt) {
    // fully-masked tile: out = (-(1-pad)*NEG - NEG)/8, constant per column
    int c4 = (t & 31) * 4;
    int r0 = t >> 5;                  // 0..7
    int n = nT + c4;
    float4 pad4 = *(const float4*)&tl[bb * S_ + n];
    f32x4 o;
    o.x = (-(1.0f - pad4.x) * NEG_ - NEG_) * 0.125f;
    o.y = (-(1.0f - pad4.y) * NEG_ - NEG_) * 0.125f;
    o.z = (-(1.0f - pad4.z) * NEG_ - NEG_) * 0.125f;
    o.w = (-(1.0f - pad4.w) * NEG_ - NEG_) * 0.125f;
#pragma unroll
    for (int r = 0; r < 16; r++) {
      int m = mT + r * 8 + r0;
      __builtin_nontemporal_store(o, (f32x4*)&out[((size_t)z * S_ + m) * S_ + n]);
    }
    return;
  }

  const unsigned short* qb = qws + ((size_t)z * S_ + mT) * D_;  // contiguous 16KB
  const unsigned short* kb = kws + ((size_t)z * S_ + nT) * D_;

  for (int c = 0; c < 4; c++) {
    int idx = c * 256 + t;
    gload_lds16(qb + idx * 8, q_lds + idx * 8);
    gload_lds16(kb + idx * 8, k_lds + idx * 8);
  }
  __syncthreads();

  f32x4 acc[4][4] = {};   // [j: n-tile][i: m-tile]
#pragma unroll
  for (int kk = 0; kk < 64; kk += 32) {
    bf16x8 qf[4], kf[4];
#pragma unroll
    for (int i = 0; i < 4; i++)
      qf[i] = *(const bf16x8*)&q_lds[(wm * 64 + i * 16 + col) * 64 + kk + quad * 8];
#pragma unroll
    for (int j = 0; j < 4; j++)
      kf[j] = *(const bf16x8*)&k_lds[(wn * 64 + j * 16 + col) * 64 + kk + quad * 8];
#pragma unroll
    for (int j = 0; j < 4; j++)
#pragma unroll
      for (int i = 0; i < 4; i++)
        acc[j][i] = __builtin_amdgcn_mfma_f32_16x16x32_bf16(kf[j], qf[i], acc[j][i], 0, 0, 0);
  }
  __syncthreads();   // everyone done reading q_lds/k_lds before stage overwrite

#pragma unroll
  for (int half = 0; half < 2; half++) {
    if (wm == half) {
#pragma unroll
      for (int i = 0; i < 4; i++) {
        int rloc = i * 16 + col;
#pragma unroll
        for (int j = 0; j < 4; j++) {
          int cloc = wn * 64 + j * 16 + quad * 4;
          float4 v;
          v.x = acc[j][i][0]; v.y = acc[j][i][1];
          v.z = acc[j][i][2]; v.w = acc[j][i][3];
          *(float4*)&stage[rloc * STG_ + cloc] = v;
        }
      }
    }
    __syncthreads();
    // all 256 threads: store 64 rows x 128 cols, fully coalesced, non-temporal
    int mbase = mT + half * 64;
#pragma unroll
    for (int r = 0; r < 8; r++) {
      int f = r * 256 + t;        // 0..2047
      int rloc = f >> 5;          // 0..63
      int c4 = (f & 31) * 4;      // 0..124
      float4 v = *(const float4*)&stage[rloc * STG_ + c4];
      int m = mbase + rloc;
      int n = nT + c4;
      float4 pad4 = *(const float4*)&tl[bb * S_ + n];
      f32x4 o;
      float x;
      x = v.x * pad4.x - (1.0f - pad4.x) * NEG_; if (m > n)     x -= NEG_; o.x = x * 0.125f;
      x = v.y * pad4.y - (1.0f - pad4.y) * NEG_; if (m > n + 1) x -= NEG_; o.y = x * 0.125f;
      x = v.z * pad4.z - (1.0f - pad4.z) * NEG_; if (m > n + 2) x -= NEG_; o.z = x * 0.125f;
      x = v.w * pad4.w - (1.0f - pad4.w) * NEG_; if (m > n + 3) x -= NEG_; o.w = x * 0.125f;
      __builtin_nontemporal_store(o, (f32x4*)&out[((size_t)z * S_ + m) * S_ + n]);
    }
    __syncthreads();   // protect stage before next half's writes
  }
}

// ---------------- launch ----------------

extern "C" void kernel_launch(void* const* d_in, const int* in_sizes, int n_in,
                              void* d_out, int out_size, void* d_ws, size_t ws_size,
                              hipStream_t stream) {
  const float* lhs  = (const float*)d_in[0];   // (4,1024,1024)
  const float* W    = (const float*)d_in[1];   // (1024,2048)
  const float* bias = (const float*)d_in[2];   // (2048,)
  const float* tl   = (const float*)d_in[3];   // (4,1024)
  float* out = (float*)d_out;

  char* ws = (char*)d_ws;
  unsigned short* lhsb = (unsigned short*)(ws);                      // 8 MB
  unsigned short* WT   = (unsigned short*)(ws + (8u  << 20));        // 4 MB
  unsigned short* qws  = (unsigned short*)(ws + (12u << 20));        // 8 MB
  unsigned short* kws  = (unsigned short*)(ws + (20u << 20));        // 8 MB
  float*          sc   = (float*)        (ws + (28u << 20));         // 256 KB

  k_prep<<<6272, 256, 0, stream>>>((const float4*)lhs, lhsb, W, WT, sc);
  k_gemm1<<<512, 256, 0, stream>>>(lhsb, WT, bias, sc, qws, kws);
  k_gemm2<<<4096, 256, 0, stream>>>(qws, kws, tl, out);
}

// Round 7
// 317.913 us; speedup vs baseline: 1.0057x; 1.0057x over previous
//
#include <hip/hip_runtime.h>
#include <hip/hip_bf16.h>
#include <stdint.h>

#define B_   4
#define S_   1024
#define H_   1024      // hidden
#define NH_  16        // ENT
#define D_   64        // INNER
#define N1_  2048      // ENT*2*INNER
#define M1_  4096      // B*S
#define NEG_ 1000000000000.0f

typedef __attribute__((ext_vector_type(8))) short bf16x8;
typedef __attribute__((ext_vector_type(4))) float f32x4;

__device__ inline void gload_lds16(const void* g, void* l) {
  __builtin_amdgcn_global_load_lds(
      (const __attribute__((address_space(1))) unsigned int*)g,
      (__attribute__((address_space(3))) unsigned int*)l, 16, 0, 0);
}

__device__ inline unsigned short f2bf(float f) {
  union { float f; uint32_t u; } a; a.f = f;
  uint32_t r = a.u + 0x7fff + ((a.u >> 16) & 1);   // RNE
  return (unsigned short)(r >> 16);
}

// ---------------- fused prep: cast + transW + sincos in one launch ----------------

__global__ __launch_bounds__(256) void k_prep(
    const float4* __restrict__ lhs4, unsigned short* __restrict__ lhsb,
    const float* __restrict__ W, unsigned short* __restrict__ WT,
    float* __restrict__ tab) {
  __shared__ float tsm[32][33];
  int b = blockIdx.x, t = threadIdx.x;
  if (b < 4096) {
    int i = b * 256 + t;          // < 1048576 always
    float4 v = lhs4[i];
    uint64_t pk = (uint64_t)f2bf(v.x) | ((uint64_t)f2bf(v.y) << 16) |
                  ((uint64_t)f2bf(v.z) << 32) | ((uint64_t)f2bf(v.w) << 48);
    ((uint64_t*)lhsb)[i] = pk;
  } else if (b < 6144) {
    int bb = b - 4096;            // 0..2047
    int nb = (bb & 63) * 32, kb = (bb >> 6) * 32;
    int tx = t & 31, ty = t >> 5; // (32,8)
    for (int r = 0; r < 4; r++)
      tsm[ty + r * 8][tx] = W[(size_t)(kb + ty + r * 8) * N1_ + nb + tx];
    __syncthreads();
    for (int r = 0; r < 4; r++)
      WT[(size_t)(nb + ty + r * 8) * H_ + kb + tx] = f2bf(tsm[tx][ty + r * 8]);
  } else {
    int i = (b - 6144) * 256 + t; // < 32768
    int pos = i >> 5, fi = i & 31;
    float freq = exp2f(-(float)fi * (13.2877123795494f / 32.0f)); // 10000^(-2fi/64)
    float ang = (float)pos * freq;
    tab[2 * i]     = sinf(ang);
    tab[2 * i + 1] = cosf(ang);
  }
}

// ---------------- stage 1: P = lhs @ W + b, fused RoPE, scatter to q/k ----------------
// Round-7: grid was the occupancy cap (512 blocks = 2/CU exactly). Tile
// 128x64 -> 1024 blocks (4/CU), acc halves (-32 VGPR), LDS 24KB. Sync
// structure = round-5 proven form: prefetch-then-compute + one barrier;
// cross-block TLP (m114) hides the barrier drain. Same MFMA chain per
// output element -> bit-identical result.

__global__ __launch_bounds__(256) void k_gemm1(
    const unsigned short* __restrict__ A,   // M1_ x H_ bf16
    const unsigned short* __restrict__ BT,  // N1_ x H_ bf16
    const float* __restrict__ bias,         // N1_
    const float* __restrict__ sc,           // sin/cos table
    unsigned short* __restrict__ qws,       // [B*NH][S][D] bf16
    unsigned short* __restrict__ kws) {
  __shared__ unsigned short a_lds[2][128 * 32];
  __shared__ unsigned short b_lds[2][64 * 32];
  int t = threadIdx.x;
  int lane = t & 63, wv = t >> 6;
  int wm = wv >> 1, wn = wv & 1;
  int col = lane & 15, quad = lane >> 4;
  int swz8 = (quad ^ ((col >> 1) & 3)) * 8;   // conflict-free phase mapping

  // swizzle: l&7 = XCD; m-tile = (k&3)*8 + xcd (32 total); n-tile = k>>2 (32 total)
  int l = blockIdx.x;                 // 0..1023
  int xcd = l & 7, k = l >> 3;        // k: 0..127
  int mBase = (((k & 3) << 3) + xcd) * 128;
  int nBase = (k >> 2) * 64;

  // per-thread staging coords (constant across K-steps)
  int idx0 = t;            // A slot 0
  int idx1 = 256 + t;      // A slot 1
  int ra0 = idx0 >> 2, ca0 = (idx0 & 3) ^ ((ra0 >> 1) & 3);
  int ra1 = idx1 >> 2, ca1 = (idx1 & 3) ^ ((ra1 >> 1) & 3);
  int rb  = t >> 2,    cb  = (t & 3) ^ ((rb >> 1) & 3);
  const unsigned short* Arow0 = A + (size_t)(mBase + ra0) * H_ + ca0 * 8;
  const unsigned short* Arow1 = A + (size_t)(mBase + ra1) * H_ + ca1 * 8;
  const unsigned short* Brow  = BT + (size_t)(nBase + rb) * H_ + cb * 8;

  f32x4 acc[2][4] = {};   // [j: n-frag][i: m-frag]

  // prologue: stage K-step 0 into buf 0
  gload_lds16(Arow0, &a_lds[0][idx0 * 8]);
  gload_lds16(Arow1, &a_lds[0][idx1 * 8]);
  gload_lds16(Brow,  &b_lds[0][t * 8]);
  __syncthreads();   // buf0 resident

  int p = 0;
  for (int kk = 0; kk < H_; kk += 32) {
    if (kk + 32 < H_) {   // prefetch next K-step into other buffer (async)
      int q = p ^ 1;
      gload_lds16(Arow0 + kk + 32, &a_lds[q][idx0 * 8]);
      gload_lds16(Arow1 + kk + 32, &a_lds[q][idx1 * 8]);
      gload_lds16(Brow  + kk + 32, &b_lds[q][t * 8]);
    }
    bf16x8 af[4], bf[2];
#pragma unroll
    for (int i = 0; i < 4; i++)
      af[i] = *(const bf16x8*)&a_lds[p][(wm * 64 + i * 16 + col) * 32 + swz8];
#pragma unroll
    for (int j = 0; j < 2; j++)
      bf[j] = *(const bf16x8*)&b_lds[p][(wn * 32 + j * 16 + col) * 32 + swz8];
#pragma unroll
    for (int j = 0; j < 2; j++)
#pragma unroll
      for (int i = 0; i < 4; i++)
        acc[j][i] = __builtin_amdgcn_mfma_f32_16x16x32_bf16(bf[j], af[i], acc[j][i], 0, 0, 0);
    __syncthreads();   // drains prefetch (vmcnt) + buf[p] reads (lgkm)
    p ^= 1;
  }

  // epilogue: bias + interleaved RoPE (pairs in-lane) + ushort4 scatter
#pragma unroll
  for (int i = 0; i < 4; i++) {
    int m = mBase + wm * 64 + i * 16 + col;      // 0..4095
    int pos = m & (S_ - 1);
    int bb = m >> 10;
#pragma unroll
    for (int j = 0; j < 2; j++) {
      int n = nBase + wn * 32 + j * 16 + quad * 4;  // 4-aligned
      int d = n & 63;
      int head = n >> 7;
      int isK = (n >> 6) & 1;
      float4 bj  = *(const float4*)&bias[n];
      float4 scv = *(const float4*)&sc[(pos * 32 + (d >> 1)) * 2]; // s0,c0,s1,c1
      float v0 = acc[j][i][0] + bj.x;
      float v1 = acc[j][i][1] + bj.y;
      float v2 = acc[j][i][2] + bj.z;
      float v3 = acc[j][i][3] + bj.w;
      float o0 = v0 * scv.y - v1 * scv.x;
      float o1 = v1 * scv.y + v0 * scv.x;
      float o2 = v2 * scv.w - v3 * scv.z;
      float o3 = v3 * scv.w + v2 * scv.z;
      unsigned short* dst = isK ? kws : qws;
      ushort4 pk;
      pk.x = f2bf(o0); pk.y = f2bf(o1); pk.z = f2bf(o2); pk.w = f2bf(o3);
      *(ushort4*)&dst[((size_t)(bb * NH_ + head) * S_ + pos) * D_ + d] = pk;
    }
  }
}

// ---------------- stage 2: logits[b,h] = Q K^T with masks ----------------
// (byte-identical to round 3 for attribution)

#define STG_ 132   // stage row stride in floats

__global__ __launch_bounds__(256) void k_gemm2(
    const unsigned short* __restrict__ qws,
    const unsigned short* __restrict__ kws,
    const float* __restrict__ tl,           // (B, S)
    float* __restrict__ out) {
  __shared__ __align__(16) char smem[64 * STG_ * 4];   // 33792 B >= 32768 B
  unsigned short* q_lds = (unsigned short*)smem;
  unsigned short* k_lds = q_lds + 128 * 64;
  float* stage = (float*)smem;

  int t = threadIdx.x;
  int lane = t & 63, wv = t >> 6, wm = wv >> 1, wn = wv & 1;
  int col = lane & 15, quad = lane >> 4;

  int l = blockIdx.x;                 // 0..4095
  int xcd = l & 7, k = l >> 3;        // k: 0..511
  int z = (xcd << 3) + (k >> 6);      // 0..63 (b*16+h)
  int tile = k & 63;
  int mt = tile >> 3, nt = tile & 7;
  int mT = mt * 128, nT = nt * 128;
  int bb = z >> 4;

  if (nt < mt) {
    // fully-masked tile: out = (-(1-pad)*NEG - NEG)/8, constant per column
    int c4 = (t & 31) * 4;
    int r0 = t >> 5;                  // 0..7
    int n = nT + c4;
    float4 pad4 = *(const float4*)&tl[bb * S_ + n];
    f32x4 o;
    o.x = (-(1.0f - pad4.x) * NEG_ - NEG_) * 0.125f;
    o.y = (-(1.0f - pad4.y) * NEG_ - NEG_) * 0.125f;
    o.z = (-(1.0f - pad4.z) * NEG_ - NEG_) * 0.125f;
    o.w = (-(1.0f - pad4.w) * NEG_ - NEG_) * 0.125f;
#pragma unroll
    for (int r = 0; r < 16; r++) {
      int m = mT + r * 8 + r0;
      __builtin_nontemporal_store(o, (f32x4*)&out[((size_t)z * S_ + m) * S_ + n]);
    }
    return;
  }

  const unsigned short* qb = qws + ((size_t)z * S_ + mT) * D_;  // contiguous 16KB
  const unsigned short* kb = kws + ((size_t)z * S_ + nT) * D_;

  for (int c = 0; c < 4; c++) {
    int idx = c * 256 + t;
    gload_lds16(qb + idx * 8, q_lds + idx * 8);
    gload_lds16(kb + idx * 8, k_lds + idx * 8);
  }
  __syncthreads();

  f32x4 acc[4][4] = {};   // [j: n-tile][i: m-tile]
#pragma unroll
  for (int kk = 0; kk < 64; kk += 32) {
    bf16x8 qf[4], kf[4];
#pragma unroll
    for (int i = 0; i < 4; i++)
      qf[i] = *(const bf16x8*)&q_lds[(wm * 64 + i * 16 + col) * 64 + kk + quad * 8];
#pragma unroll
    for (int j = 0; j < 4; j++)
      kf[j] = *(const bf16x8*)&k_lds[(wn * 64 + j * 16 + col) * 64 + kk + quad * 8];
#pragma unroll
    for (int j = 0; j < 4; j++)
#pragma unroll
      for (int i = 0; i < 4; i++)
        acc[j][i] = __builtin_amdgcn_mfma_f32_16x16x32_bf16(kf[j], qf[i], acc[j][i], 0, 0, 0);
  }
  __syncthreads();   // everyone done reading q_lds/k_lds before stage overwrite

#pragma unroll
  for (int half = 0; half < 2; half++) {
    if (wm == half) {
#pragma unroll
      for (int i = 0; i < 4; i++) {
        int rloc = i * 16 + col;
#pragma unroll
        for (int j = 0; j < 4; j++) {
          int cloc = wn * 64 + j * 16 + quad * 4;
          float4 v;
          v.x = acc[j][i][0]; v.y = acc[j][i][1];
          v.z = acc[j][i][2]; v.w = acc[j][i][3];
          *(float4*)&stage[rloc * STG_ + cloc] = v;
        }
      }
    }
    __syncthreads();
    // all 256 threads: store 64 rows x 128 cols, fully coalesced, non-temporal
    int mbase = mT + half * 64;
#pragma unroll
    for (int r = 0; r < 8; r++) {
      int f = r * 256 + t;        // 0..2047
      int rloc = f >> 5;          // 0..63
      int c4 = (f & 31) * 4;      // 0..124
      float4 v = *(const float4*)&stage[rloc * STG_ + c4];
      int m = mbase + rloc;
      int n = nT + c4;
      float4 pad4 = *(const float4*)&tl[bb * S_ + n];
      f32x4 o;
      float x;
      x = v.x * pad4.x - (1.0f - pad4.x) * NEG_; if (m > n)     x -= NEG_; o.x = x * 0.125f;
      x = v.y * pad4.y - (1.0f - pad4.y) * NEG_; if (m > n + 1) x -= NEG_; o.y = x * 0.125f;
      x = v.z * pad4.z - (1.0f - pad4.z) * NEG_; if (m > n + 2) x -= NEG_; o.z = x * 0.125f;
      x = v.w * pad4.w - (1.0f - pad4.w) * NEG_; if (m > n + 3) x -= NEG_; o.w = x * 0.125f;
      __builtin_nontemporal_store(o, (f32x4*)&out[((size_t)z * S_ + m) * S_ + n]);
    }
    __syncthreads();   // protect stage before next half's writes
  }
}

// ---------------- launch ----------------

extern "C" void kernel_launch(void* const* d_in, const int* in_sizes, int n_in,
                              void* d_out, int out_size, void* d_ws, size_t ws_size,
                              hipStream_t stream) {
  const float* lhs  = (const float*)d_in[0];   // (4,1024,1024)
  const float* W    = (const float*)d_in[1];   // (1024,2048)
  const float* bias = (const float*)d_in[2];   // (2048,)
  const float* tl   = (const float*)d_in[3];   // (4,1024)
  float* out = (float*)d_out;

  char* ws = (char*)d_ws;
  unsigned short* lhsb = (unsigned short*)(ws);                      // 8 MB
  unsigned short* WT   = (unsigned short*)(ws + (8u  << 20));        // 4 MB
  unsigned short* qws  = (unsigned short*)(ws + (12u << 20));        // 8 MB
  unsigned short* kws  = (unsigned short*)(ws + (20u << 20));        // 8 MB
  float*          sc   = (float*)        (ws + (28u << 20));         // 256 KB

  k_prep<<<6272, 256, 0, stream>>>((const float4*)lhs, lhsb, W, WT, sc);
  k_gemm1<<<1024, 256, 0, stream>>>(lhsb, WT, bias, sc, qws, kws);
  k_gemm2<<<4096, 256, 0, stream>>>(qws, kws, tl, out);
}

// Round 8
// 313.956 us; speedup vs baseline: 1.0184x; 1.0126x over previous
//
#include <hip/hip_runtime.h>
#include <hip/hip_bf16.h>
#include <stdint.h>

#define B_   4
#define S_   1024
#define H_   1024      // hidden
#define NH_  16        // ENT
#define D_   64        // INNER
#define N1_  2048      // ENT*2*INNER
#define M1_  4096      // B*S
#define NEG_ 1000000000000.0f

typedef __attribute__((ext_vector_type(8))) short bf16x8;
typedef __attribute__((ext_vector_type(4))) float f32x4;

__device__ inline void gload_lds16(const void* g, void* l) {
  __builtin_amdgcn_global_load_lds(
      (const __attribute__((address_space(1))) unsigned int*)g,
      (__attribute__((address_space(3))) unsigned int*)l, 16, 0, 0);
}

__device__ inline unsigned short f2bf(float f) {
  union { float f; uint32_t u; } a; a.f = f;
  uint32_t r = a.u + 0x7fff + ((a.u >> 16) & 1);   // RNE
  return (unsigned short)(r >> 16);
}

// ---------------- fused prep: cast + transW + sincos in one launch ----------------

__global__ __launch_bounds__(256) void k_prep(
    const float4* __restrict__ lhs4, unsigned short* __restrict__ lhsb,
    const float* __restrict__ W, unsigned short* __restrict__ WT,
    float* __restrict__ tab) {
  __shared__ float tsm[32][33];
  int b = blockIdx.x, t = threadIdx.x;
  if (b < 4096) {
    int i = b * 256 + t;          // < 1048576 always
    float4 v = lhs4[i];
    uint64_t pk = (uint64_t)f2bf(v.x) | ((uint64_t)f2bf(v.y) << 16) |
                  ((uint64_t)f2bf(v.z) << 32) | ((uint64_t)f2bf(v.w) << 48);
    ((uint64_t*)lhsb)[i] = pk;
  } else if (b < 6144) {
    int bb = b - 4096;            // 0..2047
    int nb = (bb & 63) * 32, kb = (bb >> 6) * 32;
    int tx = t & 31, ty = t >> 5; // (32,8)
    for (int r = 0; r < 4; r++)
      tsm[ty + r * 8][tx] = W[(size_t)(kb + ty + r * 8) * N1_ + nb + tx];
    __syncthreads();
    for (int r = 0; r < 4; r++)
      WT[(size_t)(nb + ty + r * 8) * H_ + kb + tx] = f2bf(tsm[tx][ty + r * 8]);
  } else {
    int i = (b - 6144) * 256 + t; // < 32768
    int pos = i >> 5, fi = i & 31;
    float freq = exp2f(-(float)fi * (13.2877123795494f / 32.0f)); // 10000^(-2fi/64)
    float ang = (float)pos * freq;
    tab[2 * i]     = sinf(ang);
    tab[2 * i + 1] = cosf(ang);
  }
}

// ---------------- stage 1: P = lhs @ W + b, fused RoPE, scatter to q/k ----------------
// Round-5 verified form (314.66us, absmax 0.03125): double-buffered LDS,
// prefetch-then-compute, one barrier per K-step, conflict-free XOR swizzle.
// Rounds 6 (counted-vmcnt) and 7 (128x64 retile) both regressed — this
// 2-barrier 128x128 structure is the verified local optimum for g1.

__global__ __launch_bounds__(256) void k_gemm1(
    const unsigned short* __restrict__ A,   // M1_ x H_ bf16
    const unsigned short* __restrict__ BT,  // N1_ x H_ bf16
    const float* __restrict__ bias,         // N1_
    const float* __restrict__ sc,           // sin/cos table
    unsigned short* __restrict__ qws,       // [B*NH][S][D] bf16
    unsigned short* __restrict__ kws) {
  __shared__ unsigned short a_lds[2][128 * 32];
  __shared__ unsigned short b_lds[2][128 * 32];
  int t = threadIdx.x;
  int lane = t & 63, wv = t >> 6;
  int wm = wv >> 1, wn = wv & 1;
  int col = lane & 15, quad = lane >> 4;
  int swz8 = (quad ^ ((col >> 1) & 3)) * 8;   // reader slot offset (shorts)

  int l = blockIdx.x;
  int xcd = l & 7, k = l >> 3;
  int mBase = (((k & 3) << 3) + xcd) * 128;   // 32 m-tiles
  int nBase = (k >> 2) * 128;                 // 16 n-tiles

  // per-thread staging coords (constant across K-steps)
  int idx0 = t;            // c=0
  int idx1 = 256 + t;      // c=1
  int r0 = idx0 >> 2, ch0 = (idx0 & 3) ^ ((r0 >> 1) & 3);
  int r1 = idx1 >> 2, ch1 = (idx1 & 3) ^ ((r1 >> 1) & 3);
  const unsigned short* Arow0 = A + (size_t)(mBase + r0) * H_ + ch0 * 8;
  const unsigned short* Arow1 = A + (size_t)(mBase + r1) * H_ + ch1 * 8;
  const unsigned short* Brow0 = BT + (size_t)(nBase + r0) * H_ + ch0 * 8;
  const unsigned short* Brow1 = BT + (size_t)(nBase + r1) * H_ + ch1 * 8;

  f32x4 acc[4][4] = {};   // [j: n-tile][i: m-tile]

  // prologue: stage K-step 0 into buf 0
  gload_lds16(Arow0, &a_lds[0][idx0 * 8]);
  gload_lds16(Brow0, &b_lds[0][idx0 * 8]);
  gload_lds16(Arow1, &a_lds[0][idx1 * 8]);
  gload_lds16(Brow1, &b_lds[0][idx1 * 8]);
  __syncthreads();   // buf0 resident

  int p = 0;
  for (int kk = 0; kk < H_; kk += 32) {
    if (kk + 32 < H_) {   // prefetch next K-step into other buffer (async)
      int q = p ^ 1;
      gload_lds16(Arow0 + kk + 32, &a_lds[q][idx0 * 8]);
      gload_lds16(Brow0 + kk + 32, &b_lds[q][idx0 * 8]);
      gload_lds16(Arow1 + kk + 32, &a_lds[q][idx1 * 8]);
      gload_lds16(Brow1 + kk + 32, &b_lds[q][idx1 * 8]);
    }
    bf16x8 af[4], bf[4];
#pragma unroll
    for (int i = 0; i < 4; i++)
      af[i] = *(const bf16x8*)&a_lds[p][(wm * 64 + i * 16 + col) * 32 + swz8];
#pragma unroll
    for (int j = 0; j < 4; j++)
      bf[j] = *(const bf16x8*)&b_lds[p][(wn * 64 + j * 16 + col) * 32 + swz8];
#pragma unroll
    for (int j = 0; j < 4; j++)
#pragma unroll
      for (int i = 0; i < 4; i++)
        acc[j][i] = __builtin_amdgcn_mfma_f32_16x16x32_bf16(bf[j], af[i], acc[j][i], 0, 0, 0);
    __syncthreads();   // drains prefetch (vmcnt) + buf[p] reads (lgkm)
    p ^= 1;
  }

  // epilogue: bias + interleaved RoPE (pairs in-lane) + ushort4 scatter
#pragma unroll
  for (int i = 0; i < 4; i++) {
    int m = mBase + wm * 64 + i * 16 + col;      // 0..4095
    int pos = m & (S_ - 1);
    int bb = m >> 10;
#pragma unroll
    for (int j = 0; j < 4; j++) {
      int n = nBase + wn * 64 + j * 16 + quad * 4;  // 4-aligned
      int d = n & 63;
      int head = n >> 7;
      int isK = (n >> 6) & 1;
      float4 bj  = *(const float4*)&bias[n];
      float4 scv = *(const float4*)&sc[(pos * 32 + (d >> 1)) * 2]; // s0,c0,s1,c1
      float v0 = acc[j][i][0] + bj.x;
      float v1 = acc[j][i][1] + bj.y;
      float v2 = acc[j][i][2] + bj.z;
      float v3 = acc[j][i][3] + bj.w;
      float o0 = v0 * scv.y - v1 * scv.x;
      float o1 = v1 * scv.y + v0 * scv.x;
      float o2 = v2 * scv.w - v3 * scv.z;
      float o3 = v3 * scv.w + v2 * scv.z;
      unsigned short* dst = isK ? kws : qws;
      ushort4 pk;
      pk.x = f2bf(o0); pk.y = f2bf(o1); pk.z = f2bf(o2); pk.w = f2bf(o3);
      *(ushort4*)&dst[((size_t)(bb * NH_ + head) * S_ + pos) * D_ + d] = pk;
    }
  }
}

// ---------------- stage 2: logits[b,h] = Q K^T with masks ----------------
// 4096 blocks + masked-tile skip (44% of tiles are pure NT store).

#define STG_ 132   // stage row stride in floats

__global__ __launch_bounds__(256) void k_gemm2(
    const unsigned short* __restrict__ qws,
    const unsigned short* __restrict__ kws,
    const float* __restrict__ tl,           // (B, S)
    float* __restrict__ out) {
  __shared__ __align__(16) char smem[64 * STG_ * 4];   // 33792 B >= 32768 B
  unsigned short* q_lds = (unsigned short*)smem;
  unsigned short* k_lds = q_lds + 128 * 64;
  float* stage = (float*)smem;

  int t = threadIdx.x;
  int lane = t & 63, wv = t >> 6, wm = wv >> 1, wn = wv & 1;
  int col = lane & 15, quad = lane >> 4;

  int l = blockIdx.x;                 // 0..4095
  int xcd = l & 7, k = l >> 3;        // k: 0..511
  int z = (xcd << 3) + (k >> 6);      // 0..63 (b*16+h)
  int tile = k & 63;
  int mt = tile >> 3, nt = tile & 7;
  int mT = mt * 128, nT = nt * 128;
  int bb = z >> 4;

  if (nt < mt) {
    // fully-masked tile: out = (-(1-pad)*NEG - NEG)/8, constant per column
    int c4 = (t & 31) * 4;
    int r0 = t >> 5;                  // 0..7
    int n = nT + c4;
    float4 pad4 = *(const float4*)&tl[bb * S_ + n];
    f32x4 o;
    o.x = (-(1.0f - pad4.x) * NEG_ - NEG_) * 0.125f;
    o.y = (-(1.0f - pad4.y) * NEG_ - NEG_) * 0.125f;
    o.z = (-(1.0f - pad4.z) * NEG_ - NEG_) * 0.125f;
    o.w = (-(1.0f - pad4.w) * NEG_ - NEG_) * 0.125f;
#pragma unroll
    for (int r = 0; r < 16; r++) {
      int m = mT + r * 8 + r0;
      __builtin_nontemporal_store(o, (f32x4*)&out[((size_t)z * S_ + m) * S_ + n]);
    }
    return;
  }

  const unsigned short* qb = qws + ((size_t)z * S_ + mT) * D_;  // contiguous 16KB
  const unsigned short* kb = kws + ((size_t)z * S_ + nT) * D_;

  for (int c = 0; c < 4; c++) {
    int idx = c * 256 + t;
    gload_lds16(qb + idx * 8, q_lds + idx * 8);
    gload_lds16(kb + idx * 8, k_lds + idx * 8);
  }
  __syncthreads();

  f32x4 acc[4][4] = {};   // [j: n-tile][i: m-tile]
#pragma unroll
  for (int kk = 0; kk < 64; kk += 32) {
    bf16x8 qf[4], kf[4];
#pragma unroll
    for (int i = 0; i < 4; i++)
      qf[i] = *(const bf16x8*)&q_lds[(wm * 64 + i * 16 + col) * 64 + kk + quad * 8];
#pragma unroll
    for (int j = 0; j < 4; j++)
      kf[j] = *(const bf16x8*)&k_lds[(wn * 64 + j * 16 + col) * 64 + kk + quad * 8];
#pragma unroll
    for (int j = 0; j < 4; j++)
#pragma unroll
      for (int i = 0; i < 4; i++)
        acc[j][i] = __builtin_amdgcn_mfma_f32_16x16x32_bf16(kf[j], qf[i], acc[j][i], 0, 0, 0);
  }
  __syncthreads();   // everyone done reading q_lds/k_lds before stage overwrite

#pragma unroll
  for (int half = 0; half < 2; half++) {
    if (wm == half) {
#pragma unroll
      for (int i = 0; i < 4; i++) {
        int rloc = i * 16 + col;
#pragma unroll
        for (int j = 0; j < 4; j++) {
          int cloc = wn * 64 + j * 16 + quad * 4;
          float4 v;
          v.x = acc[j][i][0]; v.y = acc[j][i][1];
          v.z = acc[j][i][2]; v.w = acc[j][i][3];
          *(float4*)&stage[rloc * STG_ + cloc] = v;
        }
      }
    }
    __syncthreads();
    // all 256 threads: store 64 rows x 128 cols, fully coalesced, non-temporal
    int mbase = mT + half * 64;
#pragma unroll
    for (int r = 0; r < 8; r++) {
      int f = r * 256 + t;        // 0..2047
      int rloc = f >> 5;          // 0..63
      int c4 = (f & 31) * 4;      // 0..124
      float4 v = *(const float4*)&stage[rloc * STG_ + c4];
      int m = mbase + rloc;
      int n = nT + c4;
      float4 pad4 = *(const float4*)&tl[bb * S_ + n];
      f32x4 o;
      float x;
      x = v.x * pad4.x - (1.0f - pad4.x) * NEG_; if (m > n)     x -= NEG_; o.x = x * 0.125f;
      x = v.y * pad4.y - (1.0f - pad4.y) * NEG_; if (m > n + 1) x -= NEG_; o.y = x * 0.125f;
      x = v.z * pad4.z - (1.0f - pad4.z) * NEG_; if (m > n + 2) x -= NEG_; o.z = x * 0.125f;
      x = v.w * pad4.w - (1.0f - pad4.w) * NEG_; if (m > n + 3) x -= NEG_; o.w = x * 0.125f;
      __builtin_nontemporal_store(o, (f32x4*)&out[((size_t)z * S_ + m) * S_ + n]);
    }
    __syncthreads();   // protect stage before next half's writes
  }
}

// ---------------- launch ----------------

extern "C" void kernel_launch(void* const* d_in, const int* in_sizes, int n_in,
                              void* d_out, int out_size, void* d_ws, size_t ws_size,
                              hipStream_t stream) {
  const float* lhs  = (const float*)d_in[0];   // (4,1024,1024)
  const float* W    = (const float*)d_in[1];   // (1024,2048)
  const float* bias = (const float*)d_in[2];   // (2048,)
  const float* tl   = (const float*)d_in[3];   // (4,1024)
  float* out = (float*)d_out;

  char* ws = (char*)d_ws;
  unsigned short* lhsb = (unsigned short*)(ws);                      // 8 MB
  unsigned short* WT   = (unsigned short*)(ws + (8u  << 20));        // 4 MB
  unsigned short* qws  = (unsigned short*)(ws + (12u << 20));        // 8 MB
  unsigned short* kws  = (unsigned short*)(ws + (20u << 20));        // 8 MB
  float*          sc   = (float*)        (ws + (28u << 20));         // 256 KB

  k_prep<<<6272, 256, 0, stream>>>((const float4*)lhs, lhsb, W, WT, sc);
  k_gemm1<<<512, 256, 0, stream>>>(lhsb, WT, bias, sc, qws, kws);
  k_gemm2<<<4096, 256, 0, stream>>>(qws, kws, tl, out);
}